// Round 1
// baseline (13700.325 us; speedup 1.0000x reference)
//
#include <hip/hip_runtime.h>
#include <hip/hip_bf16.h>

#define T_STEPS 2048
#define HDIM 256
#define G4 1024
#define NW 8
#define BATCH_SEL 63

typedef _Float16 h2 __attribute__((ext_vector_type(2)));
typedef _Float16 h8 __attribute__((ext_vector_type(8)));

__device__ __forceinline__ float fdot2f(h2 a, h2 b, float c) {
#if __has_builtin(__builtin_amdgcn_fdot2)
  return __builtin_amdgcn_fdot2(a, b, c, false);
#else
  return c + (float)a[0] * (float)b[0] + (float)a[1] * (float)b[1];
#endif
}

__device__ __forceinline__ h2 mk2(float a, float b) {
  h2 v; v[0] = (_Float16)a; v[1] = (_Float16)b; return v;
}

__device__ __forceinline__ float sigm(float x) { return 1.0f / (1.0f + __expf(-x)); }

__device__ __forceinline__ void stf(float* p, float v) {
  __hip_atomic_store(p, v, __ATOMIC_RELAXED, __HIP_MEMORY_SCOPE_AGENT);
}
__device__ __forceinline__ float ldf(const float* p) {
  return __hip_atomic_load(p, __ATOMIC_RELAXED, __HIP_MEMORY_SCOPE_AGENT);
}

// ---------------- pre: gxb[t][g] = x[63,t,:]@Wx[g,:] + bx + bh (+ peephole bias folded) ----
__global__ __launch_bounds__(256) void lstm_pre(
    const float* __restrict__ x, const float* __restrict__ Wx,
    const float* __restrict__ bx, const float* __restrict__ bh,
    const float* __restrict__ bc, float* __restrict__ gxb) {
  const int t = blockIdx.x;
  const int tid = threadIdx.x;
  __shared__ __align__(16) float xrow[256];
  xrow[tid] = x[(size_t)BATCH_SEL * T_STEPS * 256 + (size_t)t * 256 + tid];
  __syncthreads();
  const float4* xr4 = (const float4*)xrow;
  float acc[4];
#pragma unroll
  for (int gate = 0; gate < 4; ++gate) {
    int g = gate * 256 + tid;
    float b = bx[g] + bh[g];
    if (gate == 0) b += bc[tid];
    else if (gate == 1) b += bc[256 + tid];
    else if (gate == 3) b += bc[512 + tid];
    acc[gate] = b;
  }
#pragma unroll
  for (int gate = 0; gate < 4; ++gate) {
    int g = gate * 256 + tid;
    const float4* w4 = (const float4*)(Wx + (size_t)g * 256);
    float s = 0.f;
#pragma unroll 8
    for (int i2 = 0; i2 < 64; ++i2) {
      float4 wv = w4[i2]; float4 hv = xr4[i2];
      s += wv.x * hv.x + wv.y * hv.y + wv.z * hv.z + wv.w * hv.w;
    }
    acc[gate] += s;
  }
#pragma unroll
  for (int gate = 0; gate < 4; ++gate)
    gxb[(size_t)t * G4 + gate * 256 + tid] = acc[gate];
}

// ---------------- the sequential scan: 8 worker WGs, register-resident f16 weights -------
__global__ __launch_bounds__(256, 1) void lstm_scan(
    const float* __restrict__ Wh, const float* __restrict__ Wc,
    const float* __restrict__ gxb, float* __restrict__ hidden,
    float* __restrict__ pub_po, float* __restrict__ pub_c,
    float* __restrict__ pub_ao, unsigned int* __restrict__ flags) {
  if (blockIdx.x & 7) return;          // workers: 0,8,...,56 (same XCD under round-robin)
  const int w = blockIdx.x >> 3;       // 0..7
  const int tid = threadIdx.x;

  __shared__ __align__(16) _Float16 hf16[256];
  __shared__ __align__(16) _Float16 cf16[256];
  __shared__ __align__(16) _Float16 cnf16[32];
  __shared__ float cf32s[256];
  __shared__ float ghbuf[128];
  __shared__ float ppbuf[64];
  __shared__ float aosl[32];
  __shared__ float cnsl[32];

  // ---- load weights into registers as packed f16x2 ----
  const int r = tid >> 1, sub = tid & 1;        // gh: 2 threads per row
  const int gate = r >> 5, idx = r & 31;
  const int g_glob = gate * 256 + w * 32 + idx; // row of Wh
  h2 wgh[64];
  {
    const float* src = Wh + (size_t)g_glob * 256 + sub * 128;
#pragma unroll
    for (int m = 0; m < 64; ++m) wgh[m] = mk2(src[2 * m], src[2 * m + 1]);
  }
  const int rr = tid >> 2, q = tid & 3;         // pi/pf: 4 threads per row
  const int wsel = rr >> 5, pidx = rr & 31;
  h2 wpp[32];
  {
    const float* src = Wc + (size_t)(wsel * 256 + w * 32 + pidx) * 256 + q * 64;
#pragma unroll
    for (int m = 0; m < 32; ++m) wpp[m] = mk2(src[2 * m], src[2 * m + 1]);
  }
  h2 wpo[16];                                   // po: thread = output row, cols S_w
  {
    const float* src = Wc + (size_t)(512 + tid) * 256 + w * 32;
#pragma unroll
    for (int m = 0; m < 16; ++m) wpo[m] = mk2(src[2 * m], src[2 * m + 1]);
  }

  hf16[tid] = (_Float16)0.f;
  cf16[tid] = (_Float16)0.f;
  cf32s[tid] = 0.f;
  __syncthreads();

  float gx_next = gxb[g_glob];  // t = 0 prefetch (pre-kernel already done, stream order)

  const h8* hv8 = (const h8*)hf16;
  const h8* cv8 = (const h8*)cf16;
  const h8* cn8 = (const h8*)cnf16;

  for (int t = 0; t < T_STEPS; ++t) {
    const int buf = t & 1;
    // ---- phase A: gh dot (128 MACs over this thread's h-half) ----
    float acc0 = 0.f, acc1 = 0.f;
    {
      const h8* hb = hv8 + sub * 16;
#pragma unroll
      for (int m8 = 0; m8 < 16; m8 += 2) {
        h8 a = hb[m8], b = hb[m8 + 1];
        acc0 = fdot2f(wgh[4 * m8 + 0], __builtin_shufflevector(a, a, 0, 1), acc0);
        acc0 = fdot2f(wgh[4 * m8 + 1], __builtin_shufflevector(a, a, 2, 3), acc0);
        acc0 = fdot2f(wgh[4 * m8 + 2], __builtin_shufflevector(a, a, 4, 5), acc0);
        acc0 = fdot2f(wgh[4 * m8 + 3], __builtin_shufflevector(a, a, 6, 7), acc0);
        acc1 = fdot2f(wgh[4 * m8 + 4], __builtin_shufflevector(b, b, 0, 1), acc1);
        acc1 = fdot2f(wgh[4 * m8 + 5], __builtin_shufflevector(b, b, 2, 3), acc1);
        acc1 = fdot2f(wgh[4 * m8 + 6], __builtin_shufflevector(b, b, 4, 5), acc1);
        acc1 = fdot2f(wgh[4 * m8 + 7], __builtin_shufflevector(b, b, 6, 7), acc1);
      }
    }
    float acc = acc0 + acc1;
    acc += __shfl_xor(acc, 1, 64);
    float ghv = acc + gx_next;
    {
      int tn = (t + 1 < T_STEPS) ? t + 1 : T_STEPS - 1;
      gx_next = gxb[(size_t)tn * G4 + g_glob];   // prefetch, lands during sync
    }
    if (sub == 0) ghbuf[r] = ghv;
    // ---- pi/pf dots (64 MACs over this thread's c-quarter) ----
    float pa0 = 0.f, pa1 = 0.f;
    {
      const h8* cb = cv8 + q * 8;
#pragma unroll
      for (int m8 = 0; m8 < 8; m8 += 2) {
        h8 a = cb[m8], b = cb[m8 + 1];
        pa0 = fdot2f(wpp[4 * m8 + 0], __builtin_shufflevector(a, a, 0, 1), pa0);
        pa0 = fdot2f(wpp[4 * m8 + 1], __builtin_shufflevector(a, a, 2, 3), pa0);
        pa0 = fdot2f(wpp[4 * m8 + 2], __builtin_shufflevector(a, a, 4, 5), pa0);
        pa0 = fdot2f(wpp[4 * m8 + 3], __builtin_shufflevector(a, a, 6, 7), pa0);
        pa1 = fdot2f(wpp[4 * m8 + 4], __builtin_shufflevector(b, b, 0, 1), pa1);
        pa1 = fdot2f(wpp[4 * m8 + 5], __builtin_shufflevector(b, b, 2, 3), pa1);
        pa1 = fdot2f(wpp[4 * m8 + 6], __builtin_shufflevector(b, b, 4, 5), pa1);
        pa1 = fdot2f(wpp[4 * m8 + 7], __builtin_shufflevector(b, b, 6, 7), pa1);
      }
    }
    float pacc2 = pa0 + pa1;
    pacc2 += __shfl_xor(pacc2, 1, 64);
    pacc2 += __shfl_xor(pacc2, 2, 64);
    if (q == 0) ppbuf[rr] = pacc2;
    __syncthreads();
    // ---- gates + c_new on slice (32 lanes) ----
    if (tid < 32) {
      float pre_i = ghbuf[tid] + ppbuf[tid];
      float pre_f = ghbuf[32 + tid] + ppbuf[32 + tid];
      float gc = tanhf(ghbuf[64 + tid]);
      float iv = sigm(pre_i), fv = sigm(pre_f);
      float cn = fv * cf32s[w * 32 + tid] + iv * gc;
      cnsl[tid] = cn;
      cnf16[tid] = (_Float16)cn;
      aosl[tid] = ghbuf[96 + tid];   // o-gate pre-activation (biases folded in gxb)
    }
    __syncthreads();
    // ---- column-split peephole partial: po_k[o] = Woc[o, S_w] . c_new[S_w] ----
    float pacc = 0.f;
    {
#pragma unroll
      for (int m8 = 0; m8 < 4; ++m8) {
        h8 a = cn8[m8];
        pacc = fdot2f(wpo[4 * m8 + 0], __builtin_shufflevector(a, a, 0, 1), pacc);
        pacc = fdot2f(wpo[4 * m8 + 1], __builtin_shufflevector(a, a, 2, 3), pacc);
        pacc = fdot2f(wpo[4 * m8 + 2], __builtin_shufflevector(a, a, 4, 5), pacc);
        pacc = fdot2f(wpo[4 * m8 + 3], __builtin_shufflevector(a, a, 6, 7), pacc);
      }
    }
    // ---- publish ----
    stf(&pub_po[(size_t)buf * NW * 256 + w * 256 + tid], pacc);
    if (tid < 32) {
      stf(&pub_c[buf * 256 + w * 32 + tid], cnsl[tid]);
      stf(&pub_ao[buf * 256 + w * 32 + tid], aosl[tid]);
    }
    __threadfence();
    __syncthreads();
    if (tid == 0)
      __hip_atomic_store(&flags[w * 32], (unsigned)(t + 1),
                         __ATOMIC_RELEASE, __HIP_MEMORY_SCOPE_AGENT);
    // ---- phase B: wait for all 8 publishes of step t ----
    if (tid < NW) {
      while (__hip_atomic_load(&flags[tid * 32], __ATOMIC_ACQUIRE,
                               __HIP_MEMORY_SCOPE_AGENT) < (unsigned)(t + 1)) {}
    }
    __syncthreads();
    float po = 0.f;
#pragma unroll
    for (int j = 0; j < NW; ++j)
      po += ldf(&pub_po[(size_t)buf * NW * 256 + j * 256 + tid]);
    float cn = ldf(&pub_c[buf * 256 + tid]);
    float ao = ldf(&pub_ao[buf * 256 + tid]);
    float tc = tanhf(cn);
    float oo = sigm(ao + po) * tc;   // reference: o = sigmoid(...) * tc
    float hh = oo * tc;              // h_new = o * tc
    hf16[tid] = (_Float16)hh;
    cf16[tid] = (_Float16)cn;
    cf32s[tid] = cn;
    if ((tid >> 5) == w) hidden[(size_t)t * HDIM + tid] = hh;
    __syncthreads();
  }
}

// ---------------- post: logits + log_softmax, one block per t ----------------
__global__ __launch_bounds__(256) void lstm_post(
    const float* __restrict__ hidden, const float* __restrict__ Wout,
    const float* __restrict__ bout, float* __restrict__ out) {
  const int t = blockIdx.x, tid = threadIdx.x;
  __shared__ __align__(16) float hrow[256];
  __shared__ float redbuf[8];
  hrow[tid] = hidden[(size_t)t * 256 + tid];
  __syncthreads();
  const float4* h4 = (const float4*)hrow;
  float acc[2];
#pragma unroll
  for (int p = 0; p < 2; ++p) {
    int o = p * 256 + tid;
    const float4* w4 = (const float4*)(Wout + (size_t)o * 256);
    float s = bout[o];
#pragma unroll 8
    for (int i2 = 0; i2 < 64; ++i2) {
      float4 wv = w4[i2], hv = h4[i2];
      s += wv.x * hv.x + wv.y * hv.y + wv.z * hv.z + wv.w * hv.w;
    }
    acc[p] = s;
  }
  float m = fmaxf(acc[0], acc[1]);
#pragma unroll
  for (int d = 1; d < 64; d <<= 1) m = fmaxf(m, __shfl_xor(m, d, 64));
  if ((tid & 63) == 0) redbuf[tid >> 6] = m;
  __syncthreads();
  m = fmaxf(fmaxf(redbuf[0], redbuf[1]), fmaxf(redbuf[2], redbuf[3]));
  float se = __expf(acc[0] - m) + __expf(acc[1] - m);
#pragma unroll
  for (int d = 1; d < 64; d <<= 1) se += __shfl_xor(se, d, 64);
  if ((tid & 63) == 0) redbuf[4 + (tid >> 6)] = se;
  __syncthreads();
  se = (redbuf[4] + redbuf[5]) + (redbuf[6] + redbuf[7]);
  float lse = m + logf(se);
  out[(size_t)t * 512 + tid] = acc[0] - lse;
  out[(size_t)t * 512 + 256 + tid] = acc[1] - lse;
}

extern "C" void kernel_launch(void* const* d_in, const int* in_sizes, int n_in,
                              void* d_out, int out_size, void* d_ws, size_t ws_size,
                              hipStream_t stream) {
  (void)in_sizes; (void)n_in; (void)out_size; (void)ws_size;
  const float* x    = (const float*)d_in[0];
  const float* Wx   = (const float*)d_in[1];
  const float* bx   = (const float*)d_in[2];
  const float* Wh   = (const float*)d_in[3];
  const float* bh   = (const float*)d_in[4];
  const float* Wc   = (const float*)d_in[5];
  const float* bc   = (const float*)d_in[6];
  const float* Wout = (const float*)d_in[7];
  const float* bout = (const float*)d_in[8];
  float* out = (float*)d_out;

  float* gxb    = (float*)d_ws;                           // 2048*1024 f32 (8 MB)
  float* hidden = gxb + (size_t)T_STEPS * G4;             // 2048*256 f32 (2 MB)
  float* pub_po = hidden + (size_t)T_STEPS * HDIM;        // 2*8*256
  float* pub_c  = pub_po + 2 * NW * 256;                  // 2*256
  float* pub_ao = pub_c + 2 * 256;                        // 2*256
  unsigned int* flags = (unsigned int*)(pub_ao + 2 * 256); // 8*32 u32

  hipMemsetAsync(flags, 0, NW * 32 * sizeof(unsigned int), stream);
  lstm_pre<<<T_STEPS, 256, 0, stream>>>(x, Wx, bx, bh, bc, gxb);
  lstm_scan<<<64, 256, 0, stream>>>(Wh, Wc, gxb, hidden, pub_po, pub_c, pub_ao, flags);
  lstm_post<<<T_STEPS, 256, 0, stream>>>(hidden, Wout, bout, out);
}

// Round 2
// 6713.053 us; speedup vs baseline: 2.0408x; 2.0408x over previous
//
#include <hip/hip_runtime.h>
#include <hip/hip_bf16.h>

#define T_STEPS 2048
#define HDIM 256
#define G4 1024
#define NW 16          // worker workgroups; each owns 16 hidden indices
#define BATCH_SEL 63

typedef _Float16 h2 __attribute__((ext_vector_type(2)));
typedef _Float16 h8 __attribute__((ext_vector_type(8)));

__device__ __forceinline__ float fdot2f(h2 a, h2 b, float c) {
#if __has_builtin(__builtin_amdgcn_fdot2)
  return __builtin_amdgcn_fdot2(a, b, c, false);
#else
  return c + (float)a[0] * (float)b[0] + (float)a[1] * (float)b[1];
#endif
}

__device__ __forceinline__ float sigm(float x) { return 1.0f / (1.0f + __expf(-x)); }

// RELAXED agent-scope ops only: sc1 access (bypass L2 to coherent LLC), NO
// buffer_inv / buffer_wbl2 cache maintenance (those come from acquire/release
// and were the R1 killer: per-step L2 invalidation).
__device__ __forceinline__ void stf(float* p, float v) {
  __hip_atomic_store(p, v, __ATOMIC_RELAXED, __HIP_MEMORY_SCOPE_AGENT);
}
__device__ __forceinline__ float ldf(const float* p) {
  return __hip_atomic_load(p, __ATOMIC_RELAXED, __HIP_MEMORY_SCOPE_AGENT);
}
__device__ __forceinline__ void stu(unsigned* p, unsigned v) {
  __hip_atomic_store(p, v, __ATOMIC_RELAXED, __HIP_MEMORY_SCOPE_AGENT);
}
__device__ __forceinline__ unsigned ldu(const unsigned* p) {
  return __hip_atomic_load(p, __ATOMIC_RELAXED, __HIP_MEMORY_SCOPE_AGENT);
}

#define DOT8(ACC, WV, HV)                                                   \
  do {                                                                      \
    ACC = fdot2f(__builtin_shufflevector(WV, WV, 0, 1),                     \
                 __builtin_shufflevector(HV, HV, 0, 1), ACC);               \
    ACC = fdot2f(__builtin_shufflevector(WV, WV, 2, 3),                     \
                 __builtin_shufflevector(HV, HV, 2, 3), ACC);               \
    ACC = fdot2f(__builtin_shufflevector(WV, WV, 4, 5),                     \
                 __builtin_shufflevector(HV, HV, 4, 5), ACC);               \
    ACC = fdot2f(__builtin_shufflevector(WV, WV, 6, 7),                     \
                 __builtin_shufflevector(HV, HV, 6, 7), ACC);               \
  } while (0)

// ---------------- pre: gxb[t][g] = x[63,t,:]@Wx[g,:] + bx + bh (+ peephole bias) ----
__global__ __launch_bounds__(256) void lstm_pre(
    const float* __restrict__ x, const float* __restrict__ Wx,
    const float* __restrict__ bx, const float* __restrict__ bh,
    const float* __restrict__ bc, float* __restrict__ gxb) {
  const int t = blockIdx.x;
  const int tid = threadIdx.x;
  __shared__ __align__(16) float xrow[256];
  xrow[tid] = x[(size_t)BATCH_SEL * T_STEPS * 256 + (size_t)t * 256 + tid];
  __syncthreads();
  const float4* xr4 = (const float4*)xrow;
  float acc[4];
#pragma unroll
  for (int gate = 0; gate < 4; ++gate) {
    int g = gate * 256 + tid;
    float b = bx[g] + bh[g];
    if (gate == 0) b += bc[tid];
    else if (gate == 1) b += bc[256 + tid];
    else if (gate == 3) b += bc[512 + tid];
    acc[gate] = b;
  }
#pragma unroll
  for (int gate = 0; gate < 4; ++gate) {
    int g = gate * 256 + tid;
    const float4* w4 = (const float4*)(Wx + (size_t)g * 256);
    float s = 0.f;
#pragma unroll 8
    for (int i2 = 0; i2 < 64; ++i2) {
      float4 wv = w4[i2]; float4 hv = xr4[i2];
      s += wv.x * hv.x + wv.y * hv.y + wv.z * hv.z + wv.w * hv.w;
    }
    acc[gate] += s;
  }
#pragma unroll
  for (int gate = 0; gate < 4; ++gate)
    gxb[(size_t)t * G4 + gate * 256 + tid] = acc[gate];
}

// ---------------- scan: 16 WGs, LDS-resident f16 weights in read-order layout ------
// Per WG (w): owns hidden slice S_w = [w*16, w*16+16).
//   gh rows: 4 gates x 16 = 64 rows of Wh          (4 threads/row, 64 cols each)
//   pp rows: {i,f} x 16 = 32 rows of Wc            (8 threads/row, 32 cols each)
//   po rows: all 256 rows of Woc, cols S_w         (1 thread/row, 16 cols)
// Weight LDS layout: chunk (wave, j) is 1 KB contiguous across 64 lanes ->
// conflict-free ds_read_b128.  14 chunks/thread * 16 B = 224 B/thread/step.
__global__ __launch_bounds__(256, 1) void lstm_scan(
    const float* __restrict__ Wh, const float* __restrict__ Wc,
    const float* __restrict__ gxb, float* __restrict__ hidden,
    float* __restrict__ pub_po, float* __restrict__ pub_c,
    float* __restrict__ pub_ao, unsigned int* __restrict__ flags) {
  const int w = blockIdx.x;            // 0..15
  const int tid = threadIdx.x;
  const int wave = tid >> 6, lane = tid & 63;

  __shared__ __align__(16) h8 wlds[4 * 14 * 64];   // 57344 B
  __shared__ __align__(16) _Float16 hf16[256];
  __shared__ __align__(16) _Float16 cf16[256];
  __shared__ __align__(16) _Float16 cnf16[16];
  __shared__ float cf32s[256];
  __shared__ float ghbuf[64];
  __shared__ float ppbuf[32];
  __shared__ float aosl[16];
  __shared__ float cnsl[16];

  // ---- fill weight LDS (one-time) ----
  {
    const int r_g = tid >> 2;                 // 0..63  (gate*16 + idx)
    const int gate = r_g >> 4, idx = r_g & 15;
    const int r_p = tid >> 3;                 // 0..31  (sel*16 + pidx)
    const int sel = r_p >> 4, pidx = r_p & 15;
#pragma unroll
    for (int j = 0; j < 14; ++j) {
      const float* src;
      if (j < 8)
        src = Wh + (size_t)(gate * 256 + w * 16 + idx) * 256 + (tid & 3) * 64 + j * 8;
      else if (j < 12)
        src = Wc + (size_t)(sel * 256 + w * 16 + pidx) * 256 + (tid & 7) * 32 + (j - 8) * 8;
      else
        src = Wc + (size_t)(512 + tid) * 256 + w * 16 + (j - 12) * 8;
      float4 f0 = *(const float4*)(src);
      float4 f1 = *(const float4*)(src + 4);
      h8 pk;
      pk[0] = (_Float16)f0.x; pk[1] = (_Float16)f0.y;
      pk[2] = (_Float16)f0.z; pk[3] = (_Float16)f0.w;
      pk[4] = (_Float16)f1.x; pk[5] = (_Float16)f1.y;
      pk[6] = (_Float16)f1.z; pk[7] = (_Float16)f1.w;
      wlds[(wave * 14 + j) * 64 + lane] = pk;
    }
  }
  hf16[tid] = (_Float16)0.f;
  cf16[tid] = (_Float16)0.f;
  cf32s[tid] = 0.f;
  __syncthreads();

  const int r_g = tid >> 2;
  const int gate = r_g >> 4, idx = r_g & 15;
  const int g_glob = gate * 256 + w * 16 + idx;   // gxb column for this row
  const h8* hv8 = (const h8*)hf16;
  const h8* cv8 = (const h8*)cf16;
  const h8* cn8 = (const h8*)cnf16;
  const int jbase = wave * 14;

  float gx_cur = gxb[g_glob];   // t=0 (pre kernel already completed, stream order)

  for (int t = 0; t < T_STEPS; ++t) {
    const int buf = t & 1;
    // ---- gh: Wh[row] . h  (this thread: 64 cols) ----
    float a = 0.f;
#pragma unroll
    for (int j = 0; j < 8; ++j) {
      h8 wv = wlds[(jbase + j) * 64 + lane];
      h8 hv = hv8[(tid & 3) * 8 + j];
      DOT8(a, wv, hv);
    }
    a += __shfl_xor(a, 1, 64);
    a += __shfl_xor(a, 2, 64);
    float ghv = a + gx_cur;
    {
      int tn = (t + 1 < T_STEPS) ? t + 1 : T_STEPS - 1;
      gx_cur = gxb[(size_t)tn * G4 + g_glob];   // prefetch next step
    }
    if ((tid & 3) == 0) ghbuf[r_g] = ghv;
    // ---- pp: Wic/Wfc[row] . c  (this thread: 32 cols) ----
    float p = 0.f;
#pragma unroll
    for (int j = 8; j < 12; ++j) {
      h8 wv = wlds[(jbase + j) * 64 + lane];
      h8 cvv = cv8[(tid & 7) * 4 + (j - 8)];
      DOT8(p, wv, cvv);
    }
    p += __shfl_xor(p, 1, 64);
    p += __shfl_xor(p, 2, 64);
    p += __shfl_xor(p, 4, 64);
    if ((tid & 7) == 0) ppbuf[tid >> 3] = p;
    __syncthreads();
    // ---- gates + c_new on own 16-slice ----
    if (tid < 16) {
      float pre_i = ghbuf[tid] + ppbuf[tid];
      float pre_f = ghbuf[16 + tid] + ppbuf[16 + tid];
      float gc = tanhf(ghbuf[32 + tid]);
      float cn = sigm(pre_f) * cf32s[w * 16 + tid] + sigm(pre_i) * gc;
      cnsl[tid] = cn;
      cnf16[tid] = (_Float16)cn;
      aosl[tid] = ghbuf[48 + tid];   // o-gate pre-activation (biases in gxb)
    }
    __syncthreads();
    // ---- po partial: Woc[tid, S_w] . c_new[S_w] ----
    float po = 0.f;
    {
      h8 w0 = wlds[(jbase + 12) * 64 + lane];
      h8 w1 = wlds[(jbase + 13) * 64 + lane];
      h8 c0 = cn8[0], c1 = cn8[1];
      DOT8(po, w0, c0);
      DOT8(po, w1, c1);
    }
    // ---- publish (relaxed agent stores; manual release via vmcnt+barrier) ----
    stf(&pub_po[(size_t)(buf * NW + w) * 256 + tid], po);
    if (tid < 16) {
      stf(&pub_c[buf * 256 + w * 16 + tid], cnsl[tid]);
      stf(&pub_ao[buf * 256 + w * 16 + tid], aosl[tid]);
    }
    asm volatile("s_waitcnt vmcnt(0)" ::: "memory");
    __syncthreads();                 // all waves' stores complete
    if (tid == 0) stu(&flags[w * 32], (unsigned)(t + 1));
    // ---- wait for all 16 publishes of step t ----
    if (tid < NW) {
      while (ldu(&flags[tid * 32]) < (unsigned)(t + 1)) {}
    }
    asm volatile("" ::: "memory");
    __syncthreads();
    // ---- combine: full h_new, c_new ----
    float posum = 0.f;
#pragma unroll
    for (int j = 0; j < NW; ++j)
      posum += ldf(&pub_po[(size_t)(buf * NW + j) * 256 + tid]);
    float cn = ldf(&pub_c[buf * 256 + tid]);
    float ao = ldf(&pub_ao[buf * 256 + tid]);
    float tc = tanhf(cn);
    float oo = sigm(ao + posum) * tc;   // reference: o = sigmoid(...)*tc
    float hh = oo * tc;                 // h_new = o * tc
    hf16[tid] = (_Float16)hh;
    cf16[tid] = (_Float16)cn;
    cf32s[tid] = cn;
    if ((tid >> 4) == w) hidden[(size_t)t * HDIM + tid] = hh;
    __syncthreads();
  }
}

// ---------------- post: logits + log_softmax, one block per t ----------------
__global__ __launch_bounds__(256) void lstm_post(
    const float* __restrict__ hidden, const float* __restrict__ Wout,
    const float* __restrict__ bout, float* __restrict__ out) {
  const int t = blockIdx.x, tid = threadIdx.x;
  __shared__ __align__(16) float hrow[256];
  __shared__ float redbuf[8];
  hrow[tid] = hidden[(size_t)t * 256 + tid];
  __syncthreads();
  const float4* h4 = (const float4*)hrow;
  float acc[2];
#pragma unroll
  for (int p = 0; p < 2; ++p) {
    int o = p * 256 + tid;
    const float4* w4 = (const float4*)(Wout + (size_t)o * 256);
    float s = bout[o];
#pragma unroll 8
    for (int i2 = 0; i2 < 64; ++i2) {
      float4 wv = w4[i2], hv = h4[i2];
      s += wv.x * hv.x + wv.y * hv.y + wv.z * hv.z + wv.w * hv.w;
    }
    acc[p] = s;
  }
  float m = fmaxf(acc[0], acc[1]);
#pragma unroll
  for (int d = 1; d < 64; d <<= 1) m = fmaxf(m, __shfl_xor(m, d, 64));
  if ((tid & 63) == 0) redbuf[tid >> 6] = m;
  __syncthreads();
  m = fmaxf(fmaxf(redbuf[0], redbuf[1]), fmaxf(redbuf[2], redbuf[3]));
  float se = __expf(acc[0] - m) + __expf(acc[1] - m);
#pragma unroll
  for (int d = 1; d < 64; d <<= 1) se += __shfl_xor(se, d, 64);
  if ((tid & 63) == 0) redbuf[4 + (tid >> 6)] = se;
  __syncthreads();
  se = (redbuf[4] + redbuf[5]) + (redbuf[6] + redbuf[7]);
  float lse = m + logf(se);
  out[(size_t)t * 512 + tid] = acc[0] - lse;
  out[(size_t)t * 512 + 256 + tid] = acc[1] - lse;
}

extern "C" void kernel_launch(void* const* d_in, const int* in_sizes, int n_in,
                              void* d_out, int out_size, void* d_ws, size_t ws_size,
                              hipStream_t stream) {
  (void)in_sizes; (void)n_in; (void)out_size; (void)ws_size;
  const float* x    = (const float*)d_in[0];
  const float* Wx   = (const float*)d_in[1];
  const float* bx   = (const float*)d_in[2];
  const float* Wh   = (const float*)d_in[3];
  const float* bh   = (const float*)d_in[4];
  const float* Wc   = (const float*)d_in[5];
  const float* bc   = (const float*)d_in[6];
  const float* Wout = (const float*)d_in[7];
  const float* bout = (const float*)d_in[8];
  float* out = (float*)d_out;

  float* gxb    = (float*)d_ws;                            // 2048*1024 f32 (8 MB)
  float* hidden = gxb + (size_t)T_STEPS * G4;              // 2048*256 f32 (2 MB)
  float* pub_po = hidden + (size_t)T_STEPS * HDIM;         // 2*16*256
  float* pub_c  = pub_po + 2 * NW * 256;                   // 2*256
  float* pub_ao = pub_c + 2 * 256;                         // 2*256
  unsigned int* flags = (unsigned int*)(pub_ao + 2 * 256); // 16*32 u32

  hipMemsetAsync(flags, 0, NW * 32 * sizeof(unsigned int), stream);
  lstm_pre<<<T_STEPS, 256, 0, stream>>>(x, Wx, bx, bh, bc, gxb);
  lstm_scan<<<NW, 256, 0, stream>>>(Wh, Wc, gxb, hidden, pub_po, pub_c, pub_ao, flags);
  lstm_post<<<T_STEPS, 256, 0, stream>>>(hidden, Wout, bout, out);
}